// Round 9
// baseline (17.884 us; speedup 1.0000x reference)
//
#include <hip/hip_runtime.h>

// 3x3 median blur, BORDER_REPLICATE, NHWC float32. B=64, H=224, W=224, C=3.
// R8: back to 1 output row per thread (max waves / max MLP) after R7 showed
// the kernel is latency-bound, not HBM-BW-bound (input+output fit in L3, so
// row re-reads never hit HBM; coarsening only cut parallelism).
//   - 9 independent f32x4 loads per thread, small live set (~30 floats)
//   - __launch_bounds__(256, 6): cap VGPR ~85 -> >=6 waves/SIMD
//   - 37,632 waves = 147/CU -> deep latency hiding
//   - chunked XCD swizzle (grid 9408 = 8 * 1176), nt stores (R5: -1.8us)

typedef float f32x4 __attribute__((ext_vector_type(4)));

__device__ __forceinline__ float min3f(float a, float b, float c) {
    return fminf(fminf(a, b), c);           // v_min3_f32
}
__device__ __forceinline__ float max3f(float a, float b, float c) {
    return fmaxf(fmaxf(a, b), c);           // v_max3_f32
}
__device__ __forceinline__ float med3f(float a, float b, float c) {
    return __builtin_amdgcn_fmed3f(a, b, c); // v_med3_f32
}

__global__ __launch_bounds__(256, 6) void median3x3_r8(
    const float* __restrict__ in, float* __restrict__ out)
{
    const int W = 224, H = 224;
    const int ROWF   = W * 3;      // 672 floats per row
    const int CHUNKS = ROWF / 4;   // 168 float4 chunks per row
    const int NXCD   = 8;
    const int BAND   = 9408 / NXCD; // 1176 blocks per XCD band

    int bid  = blockIdx.x;
    int virt = (bid & (NXCD - 1)) * BAND + (bid >> 3);

    int t   = virt * 256 + threadIdx.x;
    int ci  = t % CHUNKS;
    int rid = t / CHUNKS;          // b*H + h
    int h   = rid % H;

    const float* rowC = in + (size_t)rid * ROWF;
    const float* rowU = rowC + ((h > 0)     ? -ROWF : 0);
    const float* rowD = rowC + ((h < H - 1) ?  ROWF : 0);

    const int li  = (ci > 0)          ? ci - 1 : 0;
    const int riq = (ci < CHUNKS - 1) ? ci + 1 : CHUNKS - 1;
    const bool first = (ci == 0), last = (ci == CHUNKS - 1);

    // v[r][q]: row r value at chunk-relative float position q-3 (q=0..9 -> -3..6)
    float v[3][10];
    const float* rows[3] = { rowU, rowC, rowD };
    #pragma unroll
    for (int r = 0; r < 3; ++r) {
        const f32x4* rp = (const f32x4*)rows[r];
        f32x4 L = rp[li];
        f32x4 M = rp[ci];
        f32x4 R = rp[riq];
        v[r][0] = first ? M.x : L.y;   // pos -3
        v[r][1] = first ? M.y : L.z;   // pos -2
        v[r][2] = first ? M.z : L.w;   // pos -1
        v[r][3] = M.x;
        v[r][4] = M.y;
        v[r][5] = M.z;
        v[r][6] = M.w;
        v[r][7] = last ? M.y : R.x;    // pos 4
        v[r][8] = last ? M.z : R.y;    // pos 5
        v[r][9] = last ? M.w : R.z;    // pos 6
    }

    // Per-column 3-element sort (shared across the 4 outputs)
    float lo[10], me[10], hi[10];
    #pragma unroll
    for (int q = 0; q < 10; ++q) {
        lo[q] = min3f(v[0][q], v[1][q], v[2][q]);
        me[q] = med3f(v[0][q], v[1][q], v[2][q]);
        hi[q] = max3f(v[0][q], v[1][q], v[2][q]);
    }

    f32x4 o;
    o.x = med3f(max3f(lo[0], lo[3], lo[6]),
                med3f(me[0], me[3], me[6]),
                min3f(hi[0], hi[3], hi[6]));
    o.y = med3f(max3f(lo[1], lo[4], lo[7]),
                med3f(me[1], me[4], me[7]),
                min3f(hi[1], hi[4], hi[7]));
    o.z = med3f(max3f(lo[2], lo[5], lo[8]),
                med3f(me[2], me[5], me[8]),
                min3f(hi[2], hi[5], hi[8]));
    o.w = med3f(max3f(lo[3], lo[6], lo[9]),
                med3f(me[3], me[6], me[9]),
                min3f(hi[3], hi[6], hi[9]));

    f32x4* dst = (f32x4*)(out + (size_t)rid * ROWF) + ci;
    __builtin_nontemporal_store(o, dst);
}

extern "C" void kernel_launch(void* const* d_in, const int* in_sizes, int n_in,
                              void* d_out, int out_size, void* d_ws, size_t ws_size,
                              hipStream_t stream) {
    const float* x = (const float*)d_in[0];
    float* out     = (float*)d_out;

    // total threads = 64 * 224 * 168 = 2,408,448 = 9408 blocks * 256 (exact)
    const int grid  = 9408;
    const int block = 256;
    median3x3_r8<<<grid, block, 0, stream>>>(x, out);
}